// Round 2
// baseline (157.821 us; speedup 1.0000x reference)
//
#include <hip/hip_runtime.h>
#include <hip/hip_bf16.h>

typedef float f32x4 __attribute__((ext_vector_type(4)));
typedef __bf16 bf16x8 __attribute__((ext_vector_type(8)));
typedef __bf16 bf16x4 __attribute__((ext_vector_type(4)));

// ---------------------------------------------------------------------------
// convert: fp32 -> bf16 for x (2M elems) and Wq/Wk/Wv/Wo (1M each), contiguous
// ---------------------------------------------------------------------------
__global__ __launch_bounds__(256) void convert_all(
    const float* __restrict__ x, const float* __restrict__ wq,
    const float* __restrict__ wk, const float* __restrict__ wv,
    const float* __restrict__ wo, __bf16* __restrict__ dst)
{
  int t = blockIdx.x * 256 + threadIdx.x;   // 786432 threads, 8 elems each
  const float* src; size_t soff;
  if (t < 262144) { src = x; soff = (size_t)t * 8; }
  else {
    int r = (t - 262144) >> 17;
    src = (r == 0) ? wq : (r == 1) ? wk : (r == 2) ? wv : wo;
    soff = (size_t)((t - 262144) & 131071) * 8;
  }
  float4 f0 = *(const float4*)(src + soff);
  float4 f1 = *(const float4*)(src + soff + 4);
  bf16x8 o;
  o[0]=(__bf16)f0.x; o[1]=(__bf16)f0.y; o[2]=(__bf16)f0.z; o[3]=(__bf16)f0.w;
  o[4]=(__bf16)f1.x; o[5]=(__bf16)f1.y; o[6]=(__bf16)f1.z; o[7]=(__bf16)f1.w;
  *(bf16x8*)(dst + (size_t)t * 8) = o;
}

// ---------------------------------------------------------------------------
// GEMM: C[m][n] = sum_k A[m][k] * B[n][k]  (unchanged this round)
// ---------------------------------------------------------------------------
template <typename OutT>
__global__ __launch_bounds__(256) void gemm_bt(
    const __bf16* __restrict__ A,
    const __bf16* __restrict__ B0, const __bf16* __restrict__ B1, const __bf16* __restrict__ B2,
    OutT* __restrict__ C0, OutT* __restrict__ C1, OutT* __restrict__ C2,
    int M, int N, int K)
{
  const __bf16* B = (blockIdx.z == 0) ? B0 : (blockIdx.z == 1) ? B1 : B2;
  OutT* C = (blockIdx.z == 0) ? C0 : (blockIdx.z == 1) ? C1 : C2;

  __shared__ __align__(16) __bf16 As[128 * 32];
  __shared__ __align__(16) __bf16 Bs[128 * 32];

  const int tid = threadIdx.x, w = tid >> 6, l = tid & 63;
  const int wr = w >> 1, wc = w & 1;
  const int g = l >> 4, c16 = l & 15;
  const int bm = blockIdx.y, bn = blockIdx.x;

  f32x4 acc[4][4] = {};
  const int nk = K >> 5;
  const int srow = w * 32 + (l >> 2);
  const int sch  = l & 3;

  for (int kt = 0; kt < nk; ++kt) {
    bf16x8 ra[2], rb[2];
#pragma unroll
    for (int p = 0; p < 2; ++p) {
      int row = srow + p * 16;
      ra[p] = *(const bf16x8*)(A + (size_t)(bm * 128 + row) * K + kt * 32 + sch * 8);
      rb[p] = *(const bf16x8*)(B + (size_t)(bn * 128 + row) * K + kt * 32 + sch * 8);
    }
    __syncthreads();
#pragma unroll
    for (int p = 0; p < 2; ++p) {
      int row = srow + p * 16;
      int slot = sch ^ ((row >> 1) & 3);
      *(bf16x8*)((char*)As + row * 64 + slot * 16) = ra[p];
      *(bf16x8*)((char*)Bs + row * 64 + slot * 16) = rb[p];
    }
    __syncthreads();

    bf16x8 af[4], bff[4];
#pragma unroll
    for (int mt = 0; mt < 4; ++mt) {
      int row = wr * 64 + mt * 16 + c16;
      int slot = g ^ ((row >> 1) & 3);
      af[mt] = *(const bf16x8*)((char*)As + row * 64 + slot * 16);
    }
#pragma unroll
    for (int nt = 0; nt < 4; ++nt) {
      int row = wc * 64 + nt * 16 + c16;
      int slot = g ^ ((row >> 1) & 3);
      bff[nt] = *(const bf16x8*)((char*)Bs + row * 64 + slot * 16);
    }
#pragma unroll
    for (int mt = 0; mt < 4; ++mt)
#pragma unroll
      for (int nt = 0; nt < 4; ++nt)
        acc[mt][nt] = __builtin_amdgcn_mfma_f32_16x16x32_bf16(af[mt], bff[nt], acc[mt][nt], 0, 0, 0);
  }

#pragma unroll
  for (int mt = 0; mt < 4; ++mt)
#pragma unroll
    for (int nt = 0; nt < 4; ++nt)
#pragma unroll
      for (int r = 0; r < 4; ++r) {
        int row = bm * 128 + wr * 64 + mt * 16 + g * 4 + r;
        int col = bn * 128 + wc * 64 + nt * 16 + c16;
        C[(size_t)row * N + col] = (OutT)acc[mt][nt][r];
      }
}

// ---------------------------------------------------------------------------
// RoPE + justnorm + sqk scale (unchanged)
// ---------------------------------------------------------------------------
__global__ __launch_bounds__(256) void rope_norm(
    const __bf16* __restrict__ q, const __bf16* __restrict__ k,
    const float* __restrict__ sqk, __bf16* __restrict__ qo, __bf16* __restrict__ ko)
{
  int gt = blockIdx.x * 256 + threadIdx.x;
  int i = gt & 31;
  int row = gt >> 5;
  int h = row & 15;
  int n = row >> 4;

  float inv = exp2f(-(float)i * 0.415241011860919f);
  float ang = (float)n * inv;
  float s, c;
  sincosf(ang, &s, &c);

  const __bf16* qp = q + (size_t)row * 64;
  const __bf16* kp = k + (size_t)row * 64;
  float q1 = (float)qp[i], q2 = (float)qp[i + 32];
  float k1 = (float)kp[i], k2 = (float)kp[i + 32];
  float qa = q1 * c - q2 * s, qb2 = q1 * s + q2 * c;
  float ka = k1 * c - k2 * s, kb2 = k1 * s + k2 * c;

  float ssq = qa * qa + qb2 * qb2;
  float ssk = ka * ka + kb2 * kb2;
#pragma unroll
  for (int m2 = 1; m2 < 32; m2 <<= 1) {
    ssq += __shfl_xor(ssq, m2, 32);
    ssk += __shfl_xor(ssk, m2, 32);
  }
  float rq = rsqrtf(ssq), rk = rsqrtf(ssk);
  float s1 = sqk[h * 64 + i] * 32.0f;
  float s2 = sqk[h * 64 + i + 32] * 32.0f;

  qo[(size_t)row * 64 + i]      = (__bf16)(qa * rq * s1);
  qo[(size_t)row * 64 + i + 32] = (__bf16)(qb2 * rq * s2);
  ko[(size_t)row * 64 + i]      = (__bf16)(ka * rk * s1);
  ko[(size_t)row * 64 + i + 32] = (__bf16)(kb2 * rk * s2);
}

// ---------------------------------------------------------------------------
// V transpose: vt[h][d][n] = v[n][h*64+d]  (unchanged)
// ---------------------------------------------------------------------------
__global__ __launch_bounds__(256) void vtrans(const __bf16* __restrict__ v, __bf16* __restrict__ vt)
{
  __shared__ __align__(16) __bf16 t[64 * 72];
  int h = blockIdx.y;
  int n0 = blockIdx.x * 64;
  int tid = threadIdx.x;
#pragma unroll
  for (int j = 0; j < 2; ++j) {
    int idx = tid + j * 256;
    int r = idx >> 3, c = (idx & 7) * 8;
    bf16x8 val = *(const bf16x8*)(v + (size_t)(n0 + r) * 1024 + h * 64 + c);
    *(bf16x8*)&t[r * 72 + c] = val;
  }
  __syncthreads();
#pragma unroll
  for (int j = 0; j < 2; ++j) {
    int idx = tid + j * 256;
    int d = idx >> 3, nn = (idx & 7) * 8;
    bf16x8 o;
#pragma unroll
    for (int jj = 0; jj < 8; ++jj) o[jj] = t[(nn + jj) * 72 + d];
    *(bf16x8*)(vt + (size_t)(h * 64 + d) * 2048 + n0 + nn) = o;
  }
}

// ---------------------------------------------------------------------------
// Flash-decoding attention. Block = (qt, h): 16 q-rows; the 4 waves split the
// KV range (kt = w, w+4, ...). No K/V LDS staging (L2-resident: one head's K
// row = exactly 1 cacheline), ZERO barriers in the k-loop. Per-wave partial
// (m, l, O) merged once at the end via LDS.
// LDS per wave: 1056 floats = union{ Ps[16][72]bf16 (loop) ;
//                                    o[16][64]f32 + m[16] + l[16] (merge) }.
// ---------------------------------------------------------------------------
__global__ __launch_bounds__(256, 4) void attn_kernel(
    const __bf16* __restrict__ Qg, const __bf16* __restrict__ Kg,
    const __bf16* __restrict__ Vg, __bf16* __restrict__ Og)
{
  __shared__ __align__(16) float smem[4 * 1056];

  const int h = blockIdx.y;
  const int qt = 127 - blockIdx.x;           // long-first scheduling
  const int q0 = qt * 16;
  const int ktmax = (q0 + 15) >> 6;          // only this tile needs masking

  const int tid = threadIdx.x, w = tid >> 6, l = tid & 63;
  const int g = l >> 4, c16 = l & 15;

  float* region = smem + w * 1056;
  __bf16* Ps = (__bf16*)region;              // [16][72] bf16 during loop

  // Q fragments: row c16, k-chunk ks*32 + g*8 (hoisted, 2 regs of bf16x8)
  const __bf16* qbase = Qg + (size_t)(q0 + c16) * 1024 + h * 64 + g * 8;
  const bf16x8 qf0 = *(const bf16x8*)(qbase);
  const bf16x8 qf1 = *(const bf16x8*)(qbase + 32);

  f32x4 o[4] = {};
  float mrow[4], lrow[4];
#pragma unroll
  for (int r = 0; r < 4; ++r) { mrow[r] = -1e30f; lrow[r] = 0.f; }

  for (int kt = w; kt <= ktmax; kt += 4) {
    // K fragments straight from global: rows kt*64+nt*16+c16, 16B per lane
    const __bf16* kb = Kg + (size_t)(kt * 64 + c16) * 1024 + h * 64 + g * 8;
    bf16x8 kf[4][2];
#pragma unroll
    for (int nt = 0; nt < 4; ++nt) {
      kf[nt][0] = *(const bf16x8*)(kb + (size_t)nt * 16 * 1024);
      kf[nt][1] = *(const bf16x8*)(kb + (size_t)nt * 16 * 1024 + 32);
    }

    f32x4 s[4] = {};
#pragma unroll
    for (int nt = 0; nt < 4; ++nt) {
      s[nt] = __builtin_amdgcn_mfma_f32_16x16x32_bf16(qf0, kf[nt][0], s[nt], 0, 0, 0);
      s[nt] = __builtin_amdgcn_mfma_f32_16x16x32_bf16(qf1, kf[nt][1], s[nt], 0, 0, 0);
    }

    // online softmax (rows g*4+r; stats across the 16-lane group)
    const bool lastt = (kt == ktmax);
    float corr[4];
#pragma unroll
    for (int r = 0; r < 4; ++r) {
      float pv[4];
      float smax = -1e30f;
#pragma unroll
      for (int nt = 0; nt < 4; ++nt) {
        float sv = s[nt][r] * 8.0f;                     // scale = sqrt(64)
        if (lastt && (kt * 64 + nt * 16 + c16) > (q0 + g * 4 + r)) sv = -1e30f;
        pv[nt] = sv;
        smax = fmaxf(smax, sv);
      }
#pragma unroll
      for (int m2 = 1; m2 < 16; m2 <<= 1) smax = fmaxf(smax, __shfl_xor(smax, m2, 16));
      float mnew = fmaxf(mrow[r], smax);
      float cr = __expf(mrow[r] - mnew);
      corr[r] = cr;
      mrow[r] = mnew;
      float psum = 0.f;
#pragma unroll
      for (int nt = 0; nt < 4; ++nt) {
        float e = __expf(pv[nt] - mnew);
        Ps[(g * 4 + r) * 72 + nt * 16 + c16] = (__bf16)e;
        psum += e;
      }
#pragma unroll
      for (int m2 = 1; m2 < 16; m2 <<= 1) psum += __shfl_xor(psum, m2, 16);
      lrow[r] = lrow[r] * cr + psum;
    }
#pragma unroll
    for (int nt = 0; nt < 4; ++nt)
#pragma unroll
      for (int r = 0; r < 4; ++r)
        o[nt][r] *= corr[r];

    // V^T fragments (loaded after P-store to cap register pressure)
    const __bf16* vb = Vg + (size_t)(h * 64 + c16) * 2048 + kt * 64 + g * 8;
    bf16x8 vf[4][2];
#pragma unroll
    for (int nt = 0; nt < 4; ++nt) {
      vf[nt][0] = *(const bf16x8*)(vb + (size_t)nt * 16 * 2048);
      vf[nt][1] = *(const bf16x8*)(vb + (size_t)nt * 16 * 2048 + 32);
    }

    // O += P V : A = Ps rows c16 (conflict-free: stride 72 elems)
#pragma unroll
    for (int ks = 0; ks < 2; ++ks) {
      bf16x8 pa = *(const bf16x8*)((char*)Ps + c16 * 144 + ks * 64 + g * 16);
#pragma unroll
      for (int nt = 0; nt < 4; ++nt)
        o[nt] = __builtin_amdgcn_mfma_f32_16x16x32_bf16(pa, vf[nt][ks], o[nt], 0, 0, 0);
    }
  }

  // write partials into this wave's region (overlays Ps -- same wave, after use)
#pragma unroll
  for (int nt = 0; nt < 4; ++nt)
#pragma unroll
    for (int r = 0; r < 4; ++r)
      region[(g * 4 + r) * 64 + nt * 16 + c16] = o[nt][r];
  if (c16 == 0) {
#pragma unroll
    for (int r = 0; r < 4; ++r) {
      region[1024 + g * 4 + r] = mrow[r];
      region[1040 + g * 4 + r] = lrow[r];
    }
  }
  __syncthreads();

  // flash-decoding merge: thread -> (row, 4 cols)
  {
    int row = tid >> 4, c4 = (tid & 15) * 4;
    float mM = -1e30f;
#pragma unroll
    for (int ww = 0; ww < 4; ++ww) mM = fmaxf(mM, smem[ww * 1056 + 1024 + row]);
    f32x4 acc = {};
    float lacc = 0.f;
#pragma unroll
    for (int ww = 0; ww < 4; ++ww) {
      float sc = __expf(smem[ww * 1056 + 1024 + row] - mM);
      f32x4 ov = *(const f32x4*)(smem + ww * 1056 + row * 64 + c4);
      acc += ov * sc;
      lacc += sc * smem[ww * 1056 + 1040 + row];
    }
    float rinv = 1.0f / lacc;
    bf16x4 ob;
    ob[0] = (__bf16)(acc[0] * rinv); ob[1] = (__bf16)(acc[1] * rinv);
    ob[2] = (__bf16)(acc[2] * rinv); ob[3] = (__bf16)(acc[3] * rinv);
    *(bf16x4*)(Og + (size_t)(q0 + row) * 1024 + h * 64 + c4) = ob;
  }
}

// ---------------------------------------------------------------------------
extern "C" void kernel_launch(void* const* d_in, const int* in_sizes, int n_in,
                              void* d_out, int out_size, void* d_ws, size_t ws_size,
                              hipStream_t stream) {
  const float* x   = (const float*)d_in[0];
  const float* Wq  = (const float*)d_in[1];
  const float* Wk  = (const float*)d_in[2];
  const float* Wv  = (const float*)d_in[3];
  const float* Wo  = (const float*)d_in[4];
  const float* sqk = (const float*)d_in[5];
  float* out = (float*)d_out;

  __bf16* xb  = (__bf16*)d_ws;                  // [2048][1024]
  __bf16* wqb = xb  + (size_t)2048 * 1024;      // [1024][1024]
  __bf16* wkb = wqb + (size_t)1024 * 1024;
  __bf16* wvb = wkb + (size_t)1024 * 1024;
  __bf16* wob = wvb + (size_t)1024 * 1024;
  __bf16* q   = wob + (size_t)1024 * 1024;      // [2048][1024]
  __bf16* k   = q   + (size_t)2048 * 1024;
  __bf16* v   = k   + (size_t)2048 * 1024;
  __bf16* qn  = v   + (size_t)2048 * 1024;
  __bf16* kn  = qn  + (size_t)2048 * 1024;
  __bf16* vtb = kn  + (size_t)2048 * 1024;      // [16][64][2048]
  __bf16* og  = vtb + (size_t)2048 * 1024;      // [2048][1024]

  convert_all<<<3072, 256, 0, stream>>>(x, Wq, Wk, Wv, Wo, xb);
  gemm_bt<__bf16><<<dim3(8, 16, 3), 256, 0, stream>>>(
      xb, wqb, wkb, wvb, q, k, v, 2048, 1024, 1024);
  rope_norm<<<4096, 256, 0, stream>>>(q, k, sqk, qn, kn);
  vtrans<<<dim3(32, 16), 256, 0, stream>>>(v, vtb);
  attn_kernel<<<dim3(128, 16), 256, 0, stream>>>(qn, kn, vtb, og);
  gemm_bt<float><<<dim3(8, 16, 1), 256, 0, stream>>>(
      og, wob, wob, wob, out, out, out, 2048, 1024, 1024);
}

// Round 3
// 133.779 us; speedup vs baseline: 1.1797x; 1.1797x over previous
//
#include <hip/hip_runtime.h>
#include <hip/hip_bf16.h>

typedef float f32x4 __attribute__((ext_vector_type(4)));
typedef __bf16 bf16x8 __attribute__((ext_vector_type(8)));
typedef __bf16 bf16x4 __attribute__((ext_vector_type(4)));

__device__ __forceinline__ void gload_lds16(const __bf16* g, __bf16* l) {
  __builtin_amdgcn_global_load_lds(
      (const __attribute__((address_space(1))) void*)g,
      (__attribute__((address_space(3))) void*)l, 16, 0, 0);
}

// ---------------------------------------------------------------------------
// convert: fp32 -> bf16 for x (2M elems) and Wq/Wk/Wv/Wo (1M each)
// ---------------------------------------------------------------------------
__global__ __launch_bounds__(256) void convert_all(
    const float* __restrict__ x, const float* __restrict__ wq,
    const float* __restrict__ wk, const float* __restrict__ wv,
    const float* __restrict__ wo, __bf16* __restrict__ dst)
{
  int t = blockIdx.x * 256 + threadIdx.x;
  const float* src; size_t soff;
  if (t < 262144) { src = x; soff = (size_t)t * 8; }
  else {
    int r = (t - 262144) >> 17;
    src = (r == 0) ? wq : (r == 1) ? wk : (r == 2) ? wv : wo;
    soff = (size_t)((t - 262144) & 131071) * 8;
  }
  float4 f0 = *(const float4*)(src + soff);
  float4 f1 = *(const float4*)(src + soff + 4);
  bf16x8 o;
  o[0]=(__bf16)f0.x; o[1]=(__bf16)f0.y; o[2]=(__bf16)f0.z; o[3]=(__bf16)f0.w;
  o[4]=(__bf16)f1.x; o[5]=(__bf16)f1.y; o[6]=(__bf16)f1.z; o[7]=(__bf16)f1.w;
  *(bf16x8*)(dst + (size_t)t * 8) = o;
}

// ---------------------------------------------------------------------------
// GEMM: C[m][n] = sum_k A[m][k] * B[n][k]. 128x128 tile, BK=32.
// Staging via global_load_lds width=16: LDS dest linear (wave base + lane*16),
// swizzle applied on the GLOBAL source (chunk = (l&3) ^ ((row>>1)&3)); reads
// use the same XOR -> balanced banks (rule #21 both-sides-or-neither).
// ---------------------------------------------------------------------------
template <typename OutT>
__global__ __launch_bounds__(256) void gemm_bt(
    const __bf16* __restrict__ A,
    const __bf16* __restrict__ B0, const __bf16* __restrict__ B1, const __bf16* __restrict__ B2,
    OutT* __restrict__ C0, OutT* __restrict__ C1, OutT* __restrict__ C2,
    int M, int N, int K)
{
  const __bf16* B = (blockIdx.z == 0) ? B0 : (blockIdx.z == 1) ? B1 : B2;
  OutT* C = (blockIdx.z == 0) ? C0 : (blockIdx.z == 1) ? C1 : C2;

  __shared__ __align__(16) __bf16 As[128 * 32];
  __shared__ __align__(16) __bf16 Bs[128 * 32];

  const int tid = threadIdx.x, w = tid >> 6, l = tid & 63;
  const int wr = w >> 1, wc = w & 1;
  const int g = l >> 4, c16 = l & 15;
  const int bm = blockIdx.y, bn = blockIdx.x;

  f32x4 acc[4][4] = {};
  const int nk = K >> 5;
  const int lr = l >> 2, lc = l & 3;

  for (int kt = 0; kt < nk; ++kt) {
    __syncthreads();   // previous iteration's fragment reads complete
#pragma unroll
    for (int p = 0; p < 2; ++p) {
      int row = p * 64 + w * 16 + lr;
      int sch = lc ^ ((row >> 1) & 3);
      const __bf16* ga = A + (size_t)(bm * 128 + row) * K + kt * 32 + sch * 8;
      const __bf16* gb = B + (size_t)(bn * 128 + row) * K + kt * 32 + sch * 8;
      __bf16* la = As + (p * 64 + w * 16) * 32;   // wave-uniform base
      __bf16* lb = Bs + (p * 64 + w * 16) * 32;
      gload_lds16(ga, la);
      gload_lds16(gb, lb);
    }
    __syncthreads();   // drains vmcnt, tile visible to all waves

    bf16x8 af[4], bff[4];
#pragma unroll
    for (int mt = 0; mt < 4; ++mt) {
      int row = wr * 64 + mt * 16 + c16;
      int slot = g ^ ((row >> 1) & 3);
      af[mt] = *(const bf16x8*)((char*)As + row * 64 + slot * 16);
    }
#pragma unroll
    for (int nt = 0; nt < 4; ++nt) {
      int row = wc * 64 + nt * 16 + c16;
      int slot = g ^ ((row >> 1) & 3);
      bff[nt] = *(const bf16x8*)((char*)Bs + row * 64 + slot * 16);
    }
#pragma unroll
    for (int mt = 0; mt < 4; ++mt)
#pragma unroll
      for (int nt = 0; nt < 4; ++nt)
        acc[mt][nt] = __builtin_amdgcn_mfma_f32_16x16x32_bf16(af[mt], bff[nt], acc[mt][nt], 0, 0, 0);
  }

#pragma unroll
  for (int mt = 0; mt < 4; ++mt)
#pragma unroll
    for (int nt = 0; nt < 4; ++nt)
#pragma unroll
      for (int r = 0; r < 4; ++r) {
        int row = bm * 128 + wr * 64 + mt * 16 + g * 4 + r;
        int col = bn * 128 + wc * 64 + nt * 16 + c16;
        C[(size_t)row * N + col] = (OutT)acc[mt][nt][r];
      }
}

// ---------------------------------------------------------------------------
// RoPE + justnorm + sqk scale. Q additionally scaled by 8 (= sqrt(head_dim),
// the SDPA scale -- exact power of two, folded here so attn skips it).
// ---------------------------------------------------------------------------
__global__ __launch_bounds__(256) void rope_norm(
    const __bf16* __restrict__ q, const __bf16* __restrict__ k,
    const float* __restrict__ sqk, __bf16* __restrict__ qo, __bf16* __restrict__ ko)
{
  int gt = blockIdx.x * 256 + threadIdx.x;
  int i = gt & 31;
  int row = gt >> 5;
  int h = row & 15;
  int n = row >> 4;

  float inv = exp2f(-(float)i * 0.415241011860919f);
  float ang = (float)n * inv;
  float s, c;
  sincosf(ang, &s, &c);

  const __bf16* qp = q + (size_t)row * 64;
  const __bf16* kp = k + (size_t)row * 64;
  float q1 = (float)qp[i], q2 = (float)qp[i + 32];
  float k1 = (float)kp[i], k2 = (float)kp[i + 32];
  float qa = q1 * c - q2 * s, qb2 = q1 * s + q2 * c;
  float ka = k1 * c - k2 * s, kb2 = k1 * s + k2 * c;

  float ssq = qa * qa + qb2 * qb2;
  float ssk = ka * ka + kb2 * kb2;
#pragma unroll
  for (int m2 = 1; m2 < 32; m2 <<= 1) {
    ssq += __shfl_xor(ssq, m2, 32);
    ssk += __shfl_xor(ssk, m2, 32);
  }
  float rq = rsqrtf(ssq), rk = rsqrtf(ssk);
  float s1 = sqk[h * 64 + i] * 32.0f;
  float s2 = sqk[h * 64 + i + 32] * 32.0f;

  qo[(size_t)row * 64 + i]      = (__bf16)(qa * rq * s1 * 8.0f);
  qo[(size_t)row * 64 + i + 32] = (__bf16)(qb2 * rq * s2 * 8.0f);
  ko[(size_t)row * 64 + i]      = (__bf16)(ka * rk * s1);
  ko[(size_t)row * 64 + i + 32] = (__bf16)(kb2 * rk * s2);
}

// ---------------------------------------------------------------------------
// V transpose: vt[h][d][n] = v[n][h*64+d]
// ---------------------------------------------------------------------------
__global__ __launch_bounds__(256) void vtrans(const __bf16* __restrict__ v, __bf16* __restrict__ vt)
{
  __shared__ __align__(16) __bf16 t[64 * 72];
  int h = blockIdx.y;
  int n0 = blockIdx.x * 64;
  int tid = threadIdx.x;
#pragma unroll
  for (int j = 0; j < 2; ++j) {
    int idx = tid + j * 256;
    int r = idx >> 3, c = (idx & 7) * 8;
    bf16x8 val = *(const bf16x8*)(v + (size_t)(n0 + r) * 1024 + h * 64 + c);
    *(bf16x8*)&t[r * 72 + c] = val;
  }
  __syncthreads();
#pragma unroll
  for (int j = 0; j < 2; ++j) {
    int idx = tid + j * 256;
    int d = idx >> 3, nn = (idx & 7) * 8;
    bf16x8 o;
#pragma unroll
    for (int jj = 0; jj < 8; ++jj) o[jj] = t[(nn + jj) * 72 + d];
    *(bf16x8*)(vt + (size_t)(h * 64 + d) * 2048 + n0 + nn) = o;
  }
}

// ---------------------------------------------------------------------------
// Flash-decoding attention, structurally balanced: block (j, h) processes
// q-tiles j and 127-j (16 rows each); the 4 waves split the KV range.
// NO max tracking: scores bounded (~|35| worst case) so P = exp(S) directly
// in fp32; per-lane row-sum accumulated, reduced once at the end. Zero
// shuffles and zero barriers inside the k-loop.
// ---------------------------------------------------------------------------
__global__ __launch_bounds__(256, 4) void attn_kernel(
    const __bf16* __restrict__ Qg, const __bf16* __restrict__ Kg,
    const __bf16* __restrict__ Vg, __bf16* __restrict__ Og)
{
  __shared__ __align__(16) float smem[4 * 1056];

  const int h = blockIdx.y;
  const int tid = threadIdx.x, w = tid >> 6, l = tid & 63;
  const int g = l >> 4, c16 = l & 15;

  float* region = smem + w * 1056;
  __bf16* Ps = (__bf16*)region;               // [16][72] bf16 overlay (loop only)

  for (int half = 0; half < 2; ++half) {
    const int qt = half ? (127 - blockIdx.x) : blockIdx.x;
    const int q0 = qt * 16;
    const int ktmax = q0 >> 6;

    if (half) __syncthreads();                // prior merge reads fully done

    const __bf16* qbase = Qg + (size_t)(q0 + c16) * 1024 + h * 64 + g * 8;
    const bf16x8 qf0 = *(const bf16x8*)(qbase);
    const bf16x8 qf1 = *(const bf16x8*)(qbase + 32);

    f32x4 o[4] = {};
    float lsum[4] = {0.f, 0.f, 0.f, 0.f};

    for (int kt = w; kt <= ktmax; kt += 4) {
      const __bf16* kb = Kg + (size_t)(kt * 64 + c16) * 1024 + h * 64 + g * 8;
      bf16x8 kf[4][2];
#pragma unroll
      for (int nt = 0; nt < 4; ++nt) {
        kf[nt][0] = *(const bf16x8*)(kb + (size_t)nt * 16 * 1024);
        kf[nt][1] = *(const bf16x8*)(kb + (size_t)nt * 16 * 1024 + 32);
      }

      f32x4 s[4] = {};
#pragma unroll
      for (int nt = 0; nt < 4; ++nt) {
        s[nt] = __builtin_amdgcn_mfma_f32_16x16x32_bf16(qf0, kf[nt][0], s[nt], 0, 0, 0);
        s[nt] = __builtin_amdgcn_mfma_f32_16x16x32_bf16(qf1, kf[nt][1], s[nt], 0, 0, 0);
      }

      // V^T fragments issued before softmax so their latency hides under exp
      const __bf16* vb = Vg + (size_t)(h * 64 + c16) * 2048 + kt * 64 + g * 8;
      bf16x8 vf[4][2];
#pragma unroll
      for (int nt = 0; nt < 4; ++nt) {
        vf[nt][0] = *(const bf16x8*)(vb + (size_t)nt * 16 * 2048);
        vf[nt][1] = *(const bf16x8*)(vb + (size_t)nt * 16 * 2048 + 32);
      }

      // P = exp(S) (no max subtraction), causal mask only on the last tile
      const bool lastt = (kt == ktmax);
#pragma unroll
      for (int r = 0; r < 4; ++r) {
#pragma unroll
        for (int nt = 0; nt < 4; ++nt) {
          float sv = s[nt][r];
          if (lastt && (kt * 64 + nt * 16 + c16) > (q0 + g * 4 + r)) sv = -1e30f;
          float e = __expf(sv);
          Ps[(g * 4 + r) * 72 + nt * 16 + c16] = (__bf16)e;
          lsum[r] += e;
        }
      }

      // O += P V
#pragma unroll
      for (int ks = 0; ks < 2; ++ks) {
        bf16x8 pa = *(const bf16x8*)((char*)Ps + c16 * 144 + ks * 64 + g * 16);
#pragma unroll
        for (int nt = 0; nt < 4; ++nt)
          o[nt] = __builtin_amdgcn_mfma_f32_16x16x32_bf16(pa, vf[nt][ks], o[nt], 0, 0, 0);
      }
    }

    // one-time row-sum reduction across the 16-lane group
#pragma unroll
    for (int m2 = 1; m2 < 16; m2 <<= 1) {
#pragma unroll
      for (int r = 0; r < 4; ++r) lsum[r] += __shfl_xor(lsum[r], m2, 16);
    }

    // publish partials (overwrites Ps area of own wave -- safe, loop is done)
#pragma unroll
    for (int nt = 0; nt < 4; ++nt)
#pragma unroll
      for (int r = 0; r < 4; ++r)
        region[(g * 4 + r) * 64 + nt * 16 + c16] = o[nt][r];
    if (c16 == 0) {
#pragma unroll
      for (int r = 0; r < 4; ++r) region[1024 + g * 4 + r] = lsum[r];
    }
    __syncthreads();

    // merge: plain sums (no max factors), normalize, store
    {
      int row = tid >> 4, c4 = (tid & 15) * 4;
      f32x4 acc = {};
      float lacc = 0.f;
#pragma unroll
      for (int ww = 0; ww < 4; ++ww) {
        acc += *(const f32x4*)(smem + ww * 1056 + row * 64 + c4);
        lacc += smem[ww * 1056 + 1024 + row];
      }
      float rinv = 1.0f / lacc;
      bf16x4 ob;
      ob[0] = (__bf16)(acc[0] * rinv); ob[1] = (__bf16)(acc[1] * rinv);
      ob[2] = (__bf16)(acc[2] * rinv); ob[3] = (__bf16)(acc[3] * rinv);
      *(bf16x4*)(Og + (size_t)(q0 + row) * 1024 + h * 64 + c4) = ob;
    }
  }
}

// ---------------------------------------------------------------------------
extern "C" void kernel_launch(void* const* d_in, const int* in_sizes, int n_in,
                              void* d_out, int out_size, void* d_ws, size_t ws_size,
                              hipStream_t stream) {
  const float* x   = (const float*)d_in[0];
  const float* Wq  = (const float*)d_in[1];
  const float* Wk  = (const float*)d_in[2];
  const float* Wv  = (const float*)d_in[3];
  const float* Wo  = (const float*)d_in[4];
  const float* sqk = (const float*)d_in[5];
  float* out = (float*)d_out;

  __bf16* xb  = (__bf16*)d_ws;                  // [2048][1024]
  __bf16* wqb = xb  + (size_t)2048 * 1024;      // [1024][1024]
  __bf16* wkb = wqb + (size_t)1024 * 1024;
  __bf16* wvb = wkb + (size_t)1024 * 1024;
  __bf16* wob = wvb + (size_t)1024 * 1024;
  __bf16* q   = wob + (size_t)1024 * 1024;      // [2048][1024]
  __bf16* k   = q   + (size_t)2048 * 1024;
  __bf16* v   = k   + (size_t)2048 * 1024;
  __bf16* qn  = v   + (size_t)2048 * 1024;
  __bf16* kn  = qn  + (size_t)2048 * 1024;
  __bf16* vtb = kn  + (size_t)2048 * 1024;      // [16][64][2048]
  __bf16* og  = vtb + (size_t)2048 * 1024;      // [2048][1024]

  convert_all<<<3072, 256, 0, stream>>>(x, Wq, Wk, Wv, Wo, xb);
  gemm_bt<__bf16><<<dim3(8, 16, 3), 256, 0, stream>>>(
      xb, wqb, wkb, wvb, q, k, v, 2048, 1024, 1024);
  rope_norm<<<4096, 256, 0, stream>>>(q, k, sqk, qn, kn);
  vtrans<<<dim3(32, 16), 256, 0, stream>>>(v, vtb);
  attn_kernel<<<dim3(64, 16), 256, 0, stream>>>(qn, kn, vtb, og);
  gemm_bt<float><<<dim3(8, 16, 1), 256, 0, stream>>>(
      og, wob, wob, wob, out, out, out, 2048, 1024, 1024);
}

// Round 4
// 133.603 us; speedup vs baseline: 1.1813x; 1.0013x over previous
//
#include <hip/hip_runtime.h>
#include <hip/hip_bf16.h>

typedef float f32x4 __attribute__((ext_vector_type(4)));
typedef __bf16 bf16x8 __attribute__((ext_vector_type(8)));
typedef __bf16 bf16x4 __attribute__((ext_vector_type(4)));

__device__ __forceinline__ void gload_lds16(const __bf16* g, __bf16* l) {
  __builtin_amdgcn_global_load_lds(
      (const __attribute__((address_space(1))) void*)g,
      (__attribute__((address_space(3))) void*)l, 16, 0, 0);
}

// ---------------------------------------------------------------------------
// convert: fp32 -> bf16 for x (2M elems) and Wq/Wk/Wv/Wo (1M each)
// ---------------------------------------------------------------------------
__global__ __launch_bounds__(256) void convert_all(
    const float* __restrict__ x, const float* __restrict__ wq,
    const float* __restrict__ wk, const float* __restrict__ wv,
    const float* __restrict__ wo, __bf16* __restrict__ dst)
{
  int t = blockIdx.x * 256 + threadIdx.x;
  const float* src; size_t soff;
  if (t < 262144) { src = x; soff = (size_t)t * 8; }
  else {
    int r = (t - 262144) >> 17;
    src = (r == 0) ? wq : (r == 1) ? wk : (r == 2) ? wv : wo;
    soff = (size_t)((t - 262144) & 131071) * 8;
  }
  float4 f0 = *(const float4*)(src + soff);
  float4 f1 = *(const float4*)(src + soff + 4);
  bf16x8 o;
  o[0]=(__bf16)f0.x; o[1]=(__bf16)f0.y; o[2]=(__bf16)f0.z; o[3]=(__bf16)f0.w;
  o[4]=(__bf16)f1.x; o[5]=(__bf16)f1.y; o[6]=(__bf16)f1.z; o[7]=(__bf16)f1.w;
  *(bf16x8*)(dst + (size_t)t * 8) = o;
}

// ---------------------------------------------------------------------------
// GEMM: C[m][n] = sum_k A[m][k] * B[n][k]. 128x128 tile, BK=32.
// Staging via global_load_lds width=16: LDS dest linear (wave base + lane*16),
// swizzle applied on the GLOBAL source (chunk = (l&3) ^ ((row>>1)&3)); reads
// use the same XOR -> balanced banks (rule #21 both-sides-or-neither).
// ---------------------------------------------------------------------------
template <typename OutT>
__global__ __launch_bounds__(256) void gemm_bt(
    const __bf16* __restrict__ A,
    const __bf16* __restrict__ B0, const __bf16* __restrict__ B1, const __bf16* __restrict__ B2,
    OutT* __restrict__ C0, OutT* __restrict__ C1, OutT* __restrict__ C2,
    int M, int N, int K)
{
  const __bf16* B = (blockIdx.z == 0) ? B0 : (blockIdx.z == 1) ? B1 : B2;
  OutT* C = (blockIdx.z == 0) ? C0 : (blockIdx.z == 1) ? C1 : C2;

  __shared__ __align__(16) __bf16 As[128 * 32];
  __shared__ __align__(16) __bf16 Bs[128 * 32];

  const int tid = threadIdx.x, w = tid >> 6, l = tid & 63;
  const int wr = w >> 1, wc = w & 1;
  const int g = l >> 4, c16 = l & 15;
  const int bm = blockIdx.y, bn = blockIdx.x;

  f32x4 acc[4][4] = {};
  const int nk = K >> 5;
  const int lr = l >> 2, lc = l & 3;

  for (int kt = 0; kt < nk; ++kt) {
    __syncthreads();   // previous iteration's fragment reads complete
#pragma unroll
    for (int p = 0; p < 2; ++p) {
      int row = p * 64 + w * 16 + lr;
      int sch = lc ^ ((row >> 1) & 3);
      const __bf16* ga = A + (size_t)(bm * 128 + row) * K + kt * 32 + sch * 8;
      const __bf16* gb = B + (size_t)(bn * 128 + row) * K + kt * 32 + sch * 8;
      __bf16* la = As + (p * 64 + w * 16) * 32;   // wave-uniform base
      __bf16* lb = Bs + (p * 64 + w * 16) * 32;
      gload_lds16(ga, la);
      gload_lds16(gb, lb);
    }
    __syncthreads();   // drains vmcnt, tile visible to all waves

    bf16x8 af[4], bff[4];
#pragma unroll
    for (int mt = 0; mt < 4; ++mt) {
      int row = wr * 64 + mt * 16 + c16;
      int slot = g ^ ((row >> 1) & 3);
      af[mt] = *(const bf16x8*)((char*)As + row * 64 + slot * 16);
    }
#pragma unroll
    for (int nt = 0; nt < 4; ++nt) {
      int row = wc * 64 + nt * 16 + c16;
      int slot = g ^ ((row >> 1) & 3);
      bff[nt] = *(const bf16x8*)((char*)Bs + row * 64 + slot * 16);
    }
#pragma unroll
    for (int mt = 0; mt < 4; ++mt)
#pragma unroll
      for (int nt = 0; nt < 4; ++nt)
        acc[mt][nt] = __builtin_amdgcn_mfma_f32_16x16x32_bf16(af[mt], bff[nt], acc[mt][nt], 0, 0, 0);
  }

#pragma unroll
  for (int mt = 0; mt < 4; ++mt)
#pragma unroll
    for (int nt = 0; nt < 4; ++nt)
#pragma unroll
      for (int r = 0; r < 4; ++r) {
        int row = bm * 128 + wr * 64 + mt * 16 + g * 4 + r;
        int col = bn * 128 + wc * 64 + nt * 16 + c16;
        C[(size_t)row * N + col] = (OutT)acc[mt][nt][r];
      }
}

// ---------------------------------------------------------------------------
// RoPE + justnorm + sqk scale. Q additionally scaled by 8 (= sqrt(head_dim),
// the SDPA scale -- exact power of two, folded here so attn skips it).
// ---------------------------------------------------------------------------
__global__ __launch_bounds__(256) void rope_norm(
    const __bf16* __restrict__ q, const __bf16* __restrict__ k,
    const float* __restrict__ sqk, __bf16* __restrict__ qo, __bf16* __restrict__ ko)
{
  int gt = blockIdx.x * 256 + threadIdx.x;
  int i = gt & 31;
  int row = gt >> 5;
  int h = row & 15;
  int n = row >> 4;

  float inv = exp2f(-(float)i * 0.415241011860919f);
  float ang = (float)n * inv;
  float s, c;
  sincosf(ang, &s, &c);

  const __bf16* qp = q + (size_t)row * 64;
  const __bf16* kp = k + (size_t)row * 64;
  float q1 = (float)qp[i], q2 = (float)qp[i + 32];
  float k1 = (float)kp[i], k2 = (float)kp[i + 32];
  float qa = q1 * c - q2 * s, qb2 = q1 * s + q2 * c;
  float ka = k1 * c - k2 * s, kb2 = k1 * s + k2 * c;

  float ssq = qa * qa + qb2 * qb2;
  float ssk = ka * ka + kb2 * kb2;
#pragma unroll
  for (int m2 = 1; m2 < 32; m2 <<= 1) {
    ssq += __shfl_xor(ssq, m2, 32);
    ssk += __shfl_xor(ssk, m2, 32);
  }
  float rq = rsqrtf(ssq), rk = rsqrtf(ssk);
  float s1 = sqk[h * 64 + i] * 32.0f;
  float s2 = sqk[h * 64 + i + 32] * 32.0f;

  qo[(size_t)row * 64 + i]      = (__bf16)(qa * rq * s1 * 8.0f);
  qo[(size_t)row * 64 + i + 32] = (__bf16)(qb2 * rq * s2 * 8.0f);
  ko[(size_t)row * 64 + i]      = (__bf16)(ka * rk * s1);
  ko[(size_t)row * 64 + i + 32] = (__bf16)(kb2 * rk * s2);
}

// ---------------------------------------------------------------------------
// V transpose: vt[h][d][n] = v[n][h*64+d]
// ---------------------------------------------------------------------------
__global__ __launch_bounds__(256) void vtrans(const __bf16* __restrict__ v, __bf16* __restrict__ vt)
{
  __shared__ __align__(16) __bf16 t[64 * 72];
  int h = blockIdx.y;
  int n0 = blockIdx.x * 64;
  int tid = threadIdx.x;
#pragma unroll
  for (int j = 0; j < 2; ++j) {
    int idx = tid + j * 256;
    int r = idx >> 3, c = (idx & 7) * 8;
    bf16x8 val = *(const bf16x8*)(v + (size_t)(n0 + r) * 1024 + h * 64 + c);
    *(bf16x8*)&t[r * 72 + c] = val;
  }
  __syncthreads();
#pragma unroll
  for (int j = 0; j < 2; ++j) {
    int idx = tid + j * 256;
    int d = idx >> 3, nn = (idx & 7) * 8;
    bf16x8 o;
#pragma unroll
    for (int jj = 0; jj < 8; ++jj) o[jj] = t[(nn + jj) * 72 + d];
    *(bf16x8*)(vt + (size_t)(h * 64 + d) * 2048 + n0 + nn) = o;
  }
}

// ---------------------------------------------------------------------------
// Flash-decoding attention, structurally balanced: block (j, h) processes
// q-tiles j and 127-j (16 rows each); the 4 waves split the KV range.
// NO max tracking: scores bounded (~|35| worst case) so P = exp(S) directly
// in fp32; per-lane row-sum accumulated, reduced once at the end. Zero
// shuffles and zero barriers inside the k-loop.
// ---------------------------------------------------------------------------
__global__ __launch_bounds__(256, 4) void attn_kernel(
    const __bf16* __restrict__ Qg, const __bf16* __restrict__ Kg,
    const __bf16* __restrict__ Vg, __bf16* __restrict__ Og)
{
  __shared__ __align__(16) float smem[4 * 1056];

  const int h = blockIdx.y;
  const int tid = threadIdx.x, w = tid >> 6, l = tid & 63;
  const int g = l >> 4, c16 = l & 15;

  float* region = smem + w * 1056;
  __bf16* Ps = (__bf16*)region;               // [16][72] bf16 overlay (loop only)

  for (int half = 0; half < 2; ++half) {
    const int qt = half ? (127 - blockIdx.x) : blockIdx.x;
    const int q0 = qt * 16;
    const int ktmax = q0 >> 6;

    if (half) __syncthreads();                // prior merge reads fully done

    const __bf16* qbase = Qg + (size_t)(q0 + c16) * 1024 + h * 64 + g * 8;
    const bf16x8 qf0 = *(const bf16x8*)(qbase);
    const bf16x8 qf1 = *(const bf16x8*)(qbase + 32);

    f32x4 o[4] = {};
    float lsum[4] = {0.f, 0.f, 0.f, 0.f};

    for (int kt = w; kt <= ktmax; kt += 4) {
      const __bf16* kb = Kg + (size_t)(kt * 64 + c16) * 1024 + h * 64 + g * 8;
      bf16x8 kf[4][2];
#pragma unroll
      for (int nt = 0; nt < 4; ++nt) {
        kf[nt][0] = *(const bf16x8*)(kb + (size_t)nt * 16 * 1024);
        kf[nt][1] = *(const bf16x8*)(kb + (size_t)nt * 16 * 1024 + 32);
      }

      f32x4 s[4] = {};
#pragma unroll
      for (int nt = 0; nt < 4; ++nt) {
        s[nt] = __builtin_amdgcn_mfma_f32_16x16x32_bf16(qf0, kf[nt][0], s[nt], 0, 0, 0);
        s[nt] = __builtin_amdgcn_mfma_f32_16x16x32_bf16(qf1, kf[nt][1], s[nt], 0, 0, 0);
      }

      // V^T fragments issued before softmax so their latency hides under exp
      const __bf16* vb = Vg + (size_t)(h * 64 + c16) * 2048 + kt * 64 + g * 8;
      bf16x8 vf[4][2];
#pragma unroll
      for (int nt = 0; nt < 4; ++nt) {
        vf[nt][0] = *(const bf16x8*)(vb + (size_t)nt * 16 * 2048);
        vf[nt][1] = *(const bf16x8*)(vb + (size_t)nt * 16 * 2048 + 32);
      }

      // P = exp(S) (no max subtraction), causal mask only on the last tile
      const bool lastt = (kt == ktmax);
#pragma unroll
      for (int r = 0; r < 4; ++r) {
#pragma unroll
        for (int nt = 0; nt < 4; ++nt) {
          float sv = s[nt][r];
          if (lastt && (kt * 64 + nt * 16 + c16) > (q0 + g * 4 + r)) sv = -1e30f;
          float e = __expf(sv);
          Ps[(g * 4 + r) * 72 + nt * 16 + c16] = (__bf16)e;
          lsum[r] += e;
        }
      }

      // O += P V
#pragma unroll
      for (int ks = 0; ks < 2; ++ks) {
        bf16x8 pa = *(const bf16x8*)((char*)Ps + c16 * 144 + ks * 64 + g * 16);
#pragma unroll
        for (int nt = 0; nt < 4; ++nt)
          o[nt] = __builtin_amdgcn_mfma_f32_16x16x32_bf16(pa, vf[nt][ks], o[nt], 0, 0, 0);
      }
    }

    // one-time row-sum reduction across the 16-lane group
#pragma unroll
    for (int m2 = 1; m2 < 16; m2 <<= 1) {
#pragma unroll
      for (int r = 0; r < 4; ++r) lsum[r] += __shfl_xor(lsum[r], m2, 16);
    }

    // publish partials (overwrites Ps area of own wave -- safe, loop is done)
#pragma unroll
    for (int nt = 0; nt < 4; ++nt)
#pragma unroll
      for (int r = 0; r < 4; ++r)
        region[(g * 4 + r) * 64 + nt * 16 + c16] = o[nt][r];
    if (c16 == 0) {
#pragma unroll
      for (int r = 0; r < 4; ++r) region[1024 + g * 4 + r] = lsum[r];
    }
    __syncthreads();

    // merge: plain sums (no max factors), normalize, store
    {
      int row = tid >> 4, c4 = (tid & 15) * 4;
      f32x4 acc = {};
      float lacc = 0.f;
#pragma unroll
      for (int ww = 0; ww < 4; ++ww) {
        acc += *(const f32x4*)(smem + ww * 1056 + row * 64 + c4);
        lacc += smem[ww * 1056 + 1024 + row];
      }
      float rinv = 1.0f / lacc;
      bf16x4 ob;
      ob[0] = (__bf16)(acc[0] * rinv); ob[1] = (__bf16)(acc[1] * rinv);
      ob[2] = (__bf16)(acc[2] * rinv); ob[3] = (__bf16)(acc[3] * rinv);
      *(bf16x4*)(Og + (size_t)(q0 + row) * 1024 + h * 64 + c4) = ob;
    }
  }
}

// ---------------------------------------------------------------------------
extern "C" void kernel_launch(void* const* d_in, const int* in_sizes, int n_in,
                              void* d_out, int out_size, void* d_ws, size_t ws_size,
                              hipStream_t stream) {
  const float* x   = (const float*)d_in[0];
  const float* Wq  = (const float*)d_in[1];
  const float* Wk  = (const float*)d_in[2];
  const float* Wv  = (const float*)d_in[3];
  const float* Wo  = (const float*)d_in[4];
  const float* sqk = (const float*)d_in[5];
  float* out = (float*)d_out;

  __bf16* xb  = (__bf16*)d_ws;                  // [2048][1024]
  __bf16* wqb = xb  + (size_t)2048 * 1024;      // [1024][1024]
  __bf16* wkb = wqb + (size_t)1024 * 1024;
  __bf16* wvb = wkb + (size_t)1024 * 1024;
  __bf16* wob = wvb + (size_t)1024 * 1024;
  __bf16* q   = wob + (size_t)1024 * 1024;      // [2048][1024]
  __bf16* k   = q   + (size_t)2048 * 1024;
  __bf16* v   = k   + (size_t)2048 * 1024;
  __bf16* qn  = v   + (size_t)2048 * 1024;
  __bf16* kn  = qn  + (size_t)2048 * 1024;
  __bf16* vtb = kn  + (size_t)2048 * 1024;      // [16][64][2048]
  __bf16* og  = vtb + (size_t)2048 * 1024;      // [2048][1024]

  convert_all<<<3072, 256, 0, stream>>>(x, Wq, Wk, Wv, Wo, xb);
  gemm_bt<__bf16><<<dim3(8, 16, 3), 256, 0, stream>>>(
      xb, wqb, wkb, wvb, q, k, v, 2048, 1024, 1024);
  rope_norm<<<4096, 256, 0, stream>>>(q, k, sqk, qn, kn);
  vtrans<<<dim3(32, 16), 256, 0, stream>>>(v, vtb);
  attn_kernel<<<dim3(64, 16), 256, 0, stream>>>(qn, kn, vtb, og);
  gemm_bt<float><<<dim3(8, 16, 1), 256, 0, stream>>>(
      og, wob, wob, wob, out, out, out, 2048, 1024, 1024);
}